// Round 1
// baseline (1447.118 us; speedup 1.0000x reference)
//
#include <hip/hip_runtime.h>

#define DIM 1024
#define HEADS 16
#define HEAD_DIM 64
#define NTOK 49
#define SCALEF 0.125f

typedef __attribute__((ext_vector_type(8))) short bf16x8;
typedef __attribute__((ext_vector_type(4))) float floatx4;

typedef const __attribute__((address_space(1))) void* gptr_t;
typedef __attribute__((address_space(3))) void* sptr_t;

__device__ __forceinline__ void async_load16(const void* g, void* s) {
    __builtin_amdgcn_global_load_lds((gptr_t)g, (sptr_t)s, 16, 0, 0);
}

__device__ __forceinline__ unsigned short f2bf(float f) {
    unsigned int u = __builtin_bit_cast(unsigned int, f);
    u = (u + 0x7fffu + ((u >> 16) & 1u)) >> 16;
    return (unsigned short)u;
}
__device__ __forceinline__ float bf2f(unsigned short s) {
    unsigned int u = ((unsigned int)s) << 16;
    return __builtin_bit_cast(float, u);
}

// ---------------- fp32 -> bf16 convert, two arrays fused -------------------
__global__ void cvt2_kernel(const float* __restrict__ a, const float* __restrict__ b,
                            unsigned short* __restrict__ oa, unsigned short* __restrict__ ob,
                            int n) {
    int i = (blockIdx.x * 256 + threadIdx.x) * 4;
    if (i >= n) return;
    float4 va = *(const float4*)&a[i];
    float4 vb = *(const float4*)&b[i];
    ushort4 ua = make_ushort4(f2bf(va.x), f2bf(va.y), f2bf(va.z), f2bf(va.w));
    ushort4 ub = make_ushort4(f2bf(vb.x), f2bf(vb.y), f2bf(vb.z), f2bf(vb.w));
    *(ushort4*)&oa[i] = ua;
    *(ushort4*)&ob[i] = ub;
}

// ---------------- GEMM: C[m,n] = sum_k A[m,k]*B[n,k] + bias[n] -------------
// A: M x 1024 bf16 row-major. B: 1024 x 1024 bf16 row-major (row = output col).
// m97 recipe: 128x128 tile, BK=32, global_load_lds width-16, 16x16x32 MFMA.
template <bool OUT_BF16>
__global__ __launch_bounds__(256)
void gemm_bt_kernel(const unsigned short* __restrict__ A,
                    const unsigned short* __restrict__ Bw,
                    const float* __restrict__ bias,
                    void* __restrict__ Cout) {
    constexpr int K = 1024, N = 1024;
    __shared__ unsigned short As[128 * 32];
    __shared__ unsigned short Bs[128 * 32];
    const int tid = threadIdx.x;
    const int lane = tid & 63;
    const int wave = tid >> 6;
    const int wm = (wave >> 1) * 64;   // wave's row quadrant
    const int wn = (wave & 1) * 64;    // wave's col quadrant
    const int m0 = blockIdx.y * 128;
    const int n0 = blockIdx.x * 128;
    const int lr = lane & 15;          // row/col within a 16-tile
    const int lk = (lane >> 4) * 8;    // k offset within 32

    floatx4 acc[4][4] = {};

    for (int kt = 0; kt < K / 32; ++kt) {
        const int kbase = kt * 32;
#pragma unroll
        for (int j = 0; j < 2; ++j) {
            int off = tid * 16 + j * 4096;     // byte offset in 8KB tile
            int r = off >> 6;                  // row 0..127 (64B per row)
            int ce = (off & 63) >> 1;          // element offset in row
            async_load16(A + (size_t)(m0 + r) * K + kbase + ce, (char*)As + off);
            async_load16(Bw + (size_t)(n0 + r) * K + kbase + ce, (char*)Bs + off);
        }
        __syncthreads();
        bf16x8 af[4], bfr[4];
#pragma unroll
        for (int t = 0; t < 4; ++t) {
            af[t]  = *(const bf16x8*)&As[(wm + t * 16 + lr) * 32 + lk];
            bfr[t] = *(const bf16x8*)&Bs[(wn + t * 16 + lr) * 32 + lk];
        }
#pragma unroll
        for (int mt = 0; mt < 4; ++mt)
#pragma unroll
            for (int nt = 0; nt < 4; ++nt)
                acc[mt][nt] = __builtin_amdgcn_mfma_f32_16x16x32_bf16(
                    af[mt], bfr[nt], acc[mt][nt], 0, 0, 0);
        __syncthreads();
    }

    // epilogue: C/D layout col=lane&15, row=(lane>>4)*4+reg
#pragma unroll
    for (int mt = 0; mt < 4; ++mt) {
#pragma unroll
        for (int nt = 0; nt < 4; ++nt) {
            int col = n0 + wn + nt * 16 + (lane & 15);
            float bv = bias[col];
#pragma unroll
            for (int r = 0; r < 4; ++r) {
                int row = m0 + wm + mt * 16 + (lane >> 4) * 4 + r;
                float v = acc[mt][nt][r] + bv;
                if (OUT_BF16)
                    ((unsigned short*)Cout)[(size_t)row * N + col] = f2bf(v);
                else
                    ((float*)Cout)[(size_t)row * N + col] = v;
            }
        }
    }
}

// ---------------- Attention per (window, head) ------------------------------
// scores = Q K^T * scale + bias ; softmax rows ; ctx = P V  (all fp32 in LDS)
#define QKS 68   // padded row stride (floats) for Qs/Ks/Vs: breaks 64-stride bank aliasing
#define PS 50    // P row stride

__global__ __launch_bounds__(256)
void attn_kernel(const unsigned short* __restrict__ Q,
                 const unsigned short* __restrict__ K,
                 const unsigned short* __restrict__ V,
                 const float* __restrict__ bias_table,
                 const int* __restrict__ rel_idx,
                 unsigned short* __restrict__ ctx) {
    __shared__ float Qs[NTOK * QKS];
    __shared__ float Ks[NTOK * QKS];
    __shared__ float Vs[NTOK * QKS];
    __shared__ float P[NTOK * PS];

    const int tid = threadIdx.x;
    const int bh = blockIdx.x;
    const int h = bh & (HEADS - 1);
    const int b = bh >> 4;
    const size_t rowbase = (size_t)b * NTOK;
    const int colbase = h * HEAD_DIM;

    // load Q,K,V slices (49x64 bf16) -> fp32 LDS
    for (int i = tid; i < NTOK * 16; i += 256) {
        int r = i >> 4;
        int c4 = (i & 15) * 4;
        size_t g = (rowbase + r) * DIM + colbase + c4;
        ushort4 qv = *(const ushort4*)&Q[g];
        ushort4 kv = *(const ushort4*)&K[g];
        ushort4 vv = *(const ushort4*)&V[g];
        float* qd = &Qs[r * QKS + c4];
        float* kd = &Ks[r * QKS + c4];
        float* vd = &Vs[r * QKS + c4];
        qd[0] = bf2f(qv.x); qd[1] = bf2f(qv.y); qd[2] = bf2f(qv.z); qd[3] = bf2f(qv.w);
        kd[0] = bf2f(kv.x); kd[1] = bf2f(kv.y); kd[2] = bf2f(kv.z); kd[3] = bf2f(kv.w);
        vd[0] = bf2f(vv.x); vd[1] = bf2f(vv.y); vd[2] = bf2f(vv.z); vd[3] = bf2f(vv.w);
    }
    __syncthreads();

    // scores: item = (q, group of 7 k's); 49*7 = 343 items
    for (int item = tid; item < NTOK * 7; item += 256) {
        int q = item / 7;
        int k0 = (item % 7) * 7;
        float s[7] = {0.f, 0.f, 0.f, 0.f, 0.f, 0.f, 0.f};
        const float4* Qr = (const float4*)&Qs[q * QKS];
#pragma unroll 4
        for (int j4 = 0; j4 < 16; ++j4) {
            float4 qv = Qr[j4];
#pragma unroll
            for (int kk = 0; kk < 7; ++kk) {
                float4 kv = *(const float4*)&Ks[(k0 + kk) * QKS + j4 * 4];
                s[kk] += qv.x * kv.x + qv.y * kv.y + qv.z * kv.z + qv.w * kv.w;
            }
        }
#pragma unroll
        for (int kk = 0; kk < 7; ++kk) {
            int k = k0 + kk;
            float bias = bias_table[rel_idx[q * NTOK + k] * HEADS + h];
            P[q * PS + k] = s[kk] * SCALEF + bias;
        }
    }
    __syncthreads();

    // softmax: one thread per row
    if (tid < NTOK) {
        float m = -1e30f;
        for (int k = 0; k < NTOK; ++k) m = fmaxf(m, P[tid * PS + k]);
        float sum = 0.f;
        for (int k = 0; k < NTOK; ++k) {
            float e = __expf(P[tid * PS + k] - m);
            P[tid * PS + k] = e;
            sum += e;
        }
        float inv = 1.f / sum;
        for (int k = 0; k < NTOK; ++k) P[tid * PS + k] *= inv;
    }
    __syncthreads();

    // context: item = (q-group of 4, d-group of 4); 13*16 = 208 items
    if (tid < 13 * 16) {
        int q0 = (tid >> 4) * 4;
        int d4 = (tid & 15) * 4;
        float ax[4], ay[4], az[4], aw[4];
#pragma unroll
        for (int qi = 0; qi < 4; ++qi) { ax[qi] = ay[qi] = az[qi] = aw[qi] = 0.f; }
        for (int k = 0; k < NTOK; ++k) {
            float4 vv = *(const float4*)&Vs[k * QKS + d4];
#pragma unroll
            for (int qi = 0; qi < 4; ++qi) {
                float p = P[(q0 + qi) * PS + k];
                ax[qi] += p * vv.x; ay[qi] += p * vv.y;
                az[qi] += p * vv.z; aw[qi] += p * vv.w;
            }
        }
#pragma unroll
        for (int qi = 0; qi < 4; ++qi) {
            int q = q0 + qi;
            if (q < NTOK) {
                size_t g = (rowbase + q) * DIM + colbase + d4;
                *(ushort4*)&ctx[g] = make_ushort4(f2bf(ax[qi]), f2bf(ay[qi]),
                                                  f2bf(az[qi]), f2bf(aw[qi]));
            }
        }
    }
}

// ---------------- launch ----------------------------------------------------
extern "C" void kernel_launch(void* const* d_in, const int* in_sizes, int n_in,
                              void* d_out, int out_size, void* d_ws, size_t ws_size,
                              hipStream_t stream) {
    const float* landmark = (const float*)d_in[0];
    const float* image    = (const float*)d_in[1];
    const float* Wq = (const float*)d_in[2];
    const float* bq = (const float*)d_in[3];
    const float* Wk = (const float*)d_in[4];
    const float* bk = (const float*)d_in[5];
    const float* Wv = (const float*)d_in[6];
    const float* bv = (const float*)d_in[7];
    const float* Wo = (const float*)d_in[8];
    const float* bo = (const float*)d_in[9];
    const float* bias_table = (const float*)d_in[10];
    const int*   rel_idx    = (const int*)d_in[11];
    float* out = (float*)d_out;

    const size_t FEAT = (size_t)1024 * NTOK * DIM;      // 51,380,224 elements
    const size_t FB   = FEAT * 2;                        // bf16 bytes per feature buf
    const size_t WB   = (size_t)DIM * DIM * 2;           // bf16 bytes per weight
    char* ws = (char*)d_ws;
    unsigned short* Qb  = (unsigned short*)(ws + 0 * FB);
    unsigned short* Kb  = (unsigned short*)(ws + 1 * FB);
    unsigned short* Vb  = (unsigned short*)(ws + 2 * FB);
    unsigned short* Lb  = (unsigned short*)(ws + 3 * FB); // landmark bf16
    unsigned short* Ctx = (unsigned short*)(ws + 3 * FB); // aliases Lb (dead after Q GEMM)
    unsigned short* Ib  = (unsigned short*)(ws + 4 * FB); // image bf16
    unsigned short* Wqb = (unsigned short*)(ws + 5 * FB + 0 * WB);
    unsigned short* Wkb = (unsigned short*)(ws + 5 * FB + 1 * WB);
    unsigned short* Wvb = (unsigned short*)(ws + 5 * FB + 2 * WB);
    unsigned short* Wob = (unsigned short*)(ws + 5 * FB + 3 * WB);
    // total ws need: 5*FB + 4*WB = 522,190,848 bytes

    // converts
    cvt2_kernel<<<(int)(FEAT / 4 / 256), 256, 0, stream>>>(landmark, image, Lb, Ib, (int)FEAT);
    cvt2_kernel<<<(int)(DIM * DIM / 4 / 256), 256, 0, stream>>>(Wq, Wk, Wqb, Wkb, DIM * DIM);
    cvt2_kernel<<<(int)(DIM * DIM / 4 / 256), 256, 0, stream>>>(Wv, Wo, Wvb, Wob, DIM * DIM);

    // projections: M = 50176, grid (N/128, M/128)
    dim3 ggrid(1024 / 128, 50176 / 128);
    gemm_bt_kernel<true><<<ggrid, 256, 0, stream>>>(Lb, Wqb, bq, Qb);
    gemm_bt_kernel<true><<<ggrid, 256, 0, stream>>>(Ib, Wkb, bk, Kb);
    gemm_bt_kernel<true><<<ggrid, 256, 0, stream>>>(Ib, Wvb, bv, Vb);

    // attention
    attn_kernel<<<1024 * HEADS, 256, 0, stream>>>(Qb, Kb, Vb, bias_table, rel_idx, Ctx);

    // output projection -> fp32 d_out
    gemm_bt_kernel<false><<<ggrid, 256, 0, stream>>>(Ctx, Wob, bo, out);
}

// Round 2
// 1318.574 us; speedup vs baseline: 1.0975x; 1.0975x over previous
//
#include <hip/hip_runtime.h>

#define DIM 1024
#define HEADS 16
#define HEAD_DIM 64
#define NTOK 49
#define SCALEF 0.125f

typedef __attribute__((ext_vector_type(8))) short bf16x8;
typedef __attribute__((ext_vector_type(4))) float floatx4;

typedef const __attribute__((address_space(1))) void* gptr_t;
typedef __attribute__((address_space(3))) void* sptr_t;

__device__ __forceinline__ void async_load16(const void* g, void* s) {
    __builtin_amdgcn_global_load_lds((gptr_t)g, (sptr_t)s, 16, 0, 0);
}

__device__ __forceinline__ unsigned short f2bf(float f) {
    unsigned int u = __builtin_bit_cast(unsigned int, f);
    u = (u + 0x7fffu + ((u >> 16) & 1u)) >> 16;
    return (unsigned short)u;
}
__device__ __forceinline__ float bf2f(unsigned short s) {
    unsigned int u = ((unsigned int)s) << 16;
    return __builtin_bit_cast(float, u);
}

// ---------------- fp32 -> bf16 convert, two arrays fused -------------------
__global__ void cvt2_kernel(const float* __restrict__ a, const float* __restrict__ b,
                            unsigned short* __restrict__ oa, unsigned short* __restrict__ ob,
                            int n) {
    int i = (blockIdx.x * 256 + threadIdx.x) * 4;
    if (i >= n) return;
    float4 va = *(const float4*)&a[i];
    float4 vb = *(const float4*)&b[i];
    ushort4 ua = make_ushort4(f2bf(va.x), f2bf(va.y), f2bf(va.z), f2bf(va.w));
    ushort4 ub = make_ushort4(f2bf(vb.x), f2bf(vb.y), f2bf(vb.z), f2bf(vb.w));
    *(ushort4*)&oa[i] = ua;
    *(ushort4*)&ob[i] = ub;
}

// ---------------- GEMM: C[m,n] = sum_k A[m,k]*B[n,k] + bias[n] -------------
template <bool OUT_BF16>
__global__ __launch_bounds__(256)
void gemm_bt_kernel(const unsigned short* __restrict__ A,
                    const unsigned short* __restrict__ Bw,
                    const float* __restrict__ bias,
                    void* __restrict__ Cout) {
    constexpr int K = 1024, N = 1024;
    __shared__ unsigned short As[128 * 32];
    __shared__ unsigned short Bs[128 * 32];
    const int tid = threadIdx.x;
    const int lane = tid & 63;
    const int wave = tid >> 6;
    const int wm = (wave >> 1) * 64;
    const int wn = (wave & 1) * 64;
    const int m0 = blockIdx.y * 128;
    const int n0 = blockIdx.x * 128;
    const int lr = lane & 15;
    const int lk = (lane >> 4) * 8;

    floatx4 acc[4][4] = {};

    for (int kt = 0; kt < K / 32; ++kt) {
        const int kbase = kt * 32;
#pragma unroll
        for (int j = 0; j < 2; ++j) {
            int off = tid * 16 + j * 4096;
            int r = off >> 6;
            int ce = (off & 63) >> 1;
            async_load16(A + (size_t)(m0 + r) * K + kbase + ce, (char*)As + off);
            async_load16(Bw + (size_t)(n0 + r) * K + kbase + ce, (char*)Bs + off);
        }
        __syncthreads();
        bf16x8 af[4], bfr[4];
#pragma unroll
        for (int t = 0; t < 4; ++t) {
            af[t]  = *(const bf16x8*)&As[(wm + t * 16 + lr) * 32 + lk];
            bfr[t] = *(const bf16x8*)&Bs[(wn + t * 16 + lr) * 32 + lk];
        }
#pragma unroll
        for (int mt = 0; mt < 4; ++mt)
#pragma unroll
            for (int nt = 0; nt < 4; ++nt)
                acc[mt][nt] = __builtin_amdgcn_mfma_f32_16x16x32_bf16(
                    af[mt], bfr[nt], acc[mt][nt], 0, 0, 0);
        __syncthreads();
    }

#pragma unroll
    for (int mt = 0; mt < 4; ++mt) {
#pragma unroll
        for (int nt = 0; nt < 4; ++nt) {
            int col = n0 + wn + nt * 16 + (lane & 15);
            float bv = bias[col];
#pragma unroll
            for (int r = 0; r < 4; ++r) {
                int row = m0 + wm + mt * 16 + (lane >> 4) * 4 + r;
                float v = acc[mt][nt][r] + bv;
                if (OUT_BF16)
                    ((unsigned short*)Cout)[(size_t)row * N + col] = f2bf(v);
                else
                    ((float*)Cout)[(size_t)row * N + col] = v;
            }
        }
    }
}

// ---------------- bias precompute: dense [16][64][64] fp32, mask fused ------
__global__ void bias_pre_kernel(const float* __restrict__ bias_table,
                                const int* __restrict__ rel_idx,
                                float* __restrict__ bias_dense) {
    int h = blockIdx.x;
    for (int i = threadIdx.x; i < 64 * 64; i += 256) {
        int q = i >> 6, k = i & 63;
        float v;
        if (k >= NTOK) v = -1e30f;                  // mask padded key columns
        else if (q >= NTOK) v = 0.f;                // padded query rows: don't care
        else v = bias_table[rel_idx[q * NTOK + k] * HEADS + h];
        bias_dense[h * 4096 + i] = v;
    }
}

// ---------------- MFMA attention: one wave per (window, head) ---------------
// XOR-swizzled LDS: element (row, t) stored at row*64 + (t ^ ((row&7)<<3)).
// Keeps 8-short chunks contiguous + 16B aligned, spreads banks.
#define SWZ(row, t) ((t) ^ (((row) & 7) << 3))

__global__ __launch_bounds__(256)
void attn_mfma_kernel(const unsigned short* __restrict__ Q,
                      const unsigned short* __restrict__ K,
                      const unsigned short* __restrict__ V,
                      const float* __restrict__ bias_dense,
                      unsigned short* __restrict__ ctx) {
    __shared__ unsigned short Vt[4][64 * 64];  // per-wave V^T slice [d][tok]
    __shared__ unsigned short Pm[4][64 * 64];  // per-wave P slice [q][tok]

    const int tid = threadIdx.x;
    const int w = tid >> 6;
    const int lane = tid & 63;
    const int p = blockIdx.x * 4 + w;          // 4 heads of the same window per block
    const int b = p >> 4;
    const int h = p & 15;
    const size_t base = (size_t)(b * NTOK) * DIM + h * HEAD_DIM;
    unsigned short* vt = Vt[w];
    unsigned short* pm = Pm[w];

    const int lc = lane & 15;
    const int lg = lane >> 4;

    // stage V transposed into LDS; zero padded tokens 49..63
    for (int i = lane; i < 64 * 16; i += 64) {
        int tok = i >> 4, d0 = (i & 15) * 4;
        ushort4 vv = (tok < NTOK) ? *(const ushort4*)&V[base + (size_t)tok * DIM + d0]
                                  : make_ushort4(0, 0, 0, 0);
        vt[(d0 + 0) * 64 + SWZ(d0 + 0, tok)] = vv.x;
        vt[(d0 + 1) * 64 + SWZ(d0 + 1, tok)] = vv.y;
        vt[(d0 + 2) * 64 + SWZ(d0 + 2, tok)] = vv.z;
        vt[(d0 + 3) * 64 + SWZ(d0 + 3, tok)] = vv.w;
    }

    // QK^T: fragments loaded straight from global (16B contiguous)
    floatx4 acc[4][4] = {};
#pragma unroll
    for (int kt = 0; kt < 2; ++kt) {
        const int d = kt * 32 + lg * 8;
        bf16x8 af[4], bfr[4];
#pragma unroll
        for (int mt = 0; mt < 4; ++mt)
            af[mt] = *(const bf16x8*)&Q[base + (size_t)(mt * 16 + lc) * DIM + d];
#pragma unroll
        for (int nt = 0; nt < 4; ++nt)
            bfr[nt] = *(const bf16x8*)&K[base + (size_t)(nt * 16 + lc) * DIM + d];
#pragma unroll
        for (int mt = 0; mt < 4; ++mt)
#pragma unroll
            for (int nt = 0; nt < 4; ++nt)
                acc[mt][nt] = __builtin_amdgcn_mfma_f32_16x16x32_bf16(
                    af[mt], bfr[nt], acc[mt][nt], 0, 0, 0);
    }

    // scale + bias(+mask), register softmax, P -> LDS (bf16, swizzled)
    const float* bd = bias_dense + h * 4096;
#pragma unroll
    for (int mt = 0; mt < 4; ++mt) {
#pragma unroll
        for (int r = 0; r < 4; ++r) {
            const int row = mt * 16 + lg * 4 + r;
#pragma unroll
            for (int nt = 0; nt < 4; ++nt)
                acc[mt][nt][r] = acc[mt][nt][r] * SCALEF + bd[row * 64 + nt * 16 + lc];
            float mx = fmaxf(fmaxf(acc[mt][0][r], acc[mt][1][r]),
                             fmaxf(acc[mt][2][r], acc[mt][3][r]));
            mx = fmaxf(mx, __shfl_xor(mx, 1));
            mx = fmaxf(mx, __shfl_xor(mx, 2));
            mx = fmaxf(mx, __shfl_xor(mx, 4));
            mx = fmaxf(mx, __shfl_xor(mx, 8));
            float sm = 0.f;
#pragma unroll
            for (int nt = 0; nt < 4; ++nt) {
                float e = __expf(acc[mt][nt][r] - mx);
                acc[mt][nt][r] = e;
                sm += e;
            }
            sm += __shfl_xor(sm, 1);
            sm += __shfl_xor(sm, 2);
            sm += __shfl_xor(sm, 4);
            sm += __shfl_xor(sm, 8);
            const float inv = 1.f / sm;
#pragma unroll
            for (int nt = 0; nt < 4; ++nt) {
                const int col = nt * 16 + lc;
                pm[row * 64 + SWZ(row, col)] = f2bf(acc[mt][nt][r] * inv);
            }
        }
    }

    // PV: A = P (LDS), B = V^T (LDS); reuse acc as output accumulator
    floatx4 o[4][4] = {};
#pragma unroll
    for (int kt = 0; kt < 2; ++kt) {
        const int t0 = kt * 32 + lg * 8;
        bf16x8 af[4], bfr[4];
#pragma unroll
        for (int mt = 0; mt < 4; ++mt) {
            const int q = mt * 16 + lc;
            af[mt] = *(const bf16x8*)&pm[q * 64 + SWZ(q, t0)];
        }
#pragma unroll
        for (int nt = 0; nt < 4; ++nt) {
            const int dd = nt * 16 + lc;
            bfr[nt] = *(const bf16x8*)&vt[dd * 64 + SWZ(dd, t0)];
        }
#pragma unroll
        for (int mt = 0; mt < 4; ++mt)
#pragma unroll
            for (int nt = 0; nt < 4; ++nt)
                o[mt][nt] = __builtin_amdgcn_mfma_f32_16x16x32_bf16(
                    af[mt], bfr[nt], o[mt][nt], 0, 0, 0);
    }

    // store ctx (bf16), valid rows only
#pragma unroll
    for (int mt = 0; mt < 4; ++mt) {
#pragma unroll
        for (int r = 0; r < 4; ++r) {
            const int row = mt * 16 + lg * 4 + r;
            if (row < NTOK) {
#pragma unroll
                for (int nt = 0; nt < 4; ++nt)
                    ctx[base + (size_t)row * DIM + nt * 16 + lc] = f2bf(o[mt][nt][r]);
            }
        }
    }
}

// ---------------- launch ----------------------------------------------------
extern "C" void kernel_launch(void* const* d_in, const int* in_sizes, int n_in,
                              void* d_out, int out_size, void* d_ws, size_t ws_size,
                              hipStream_t stream) {
    const float* landmark = (const float*)d_in[0];
    const float* image    = (const float*)d_in[1];
    const float* Wq = (const float*)d_in[2];
    const float* bq = (const float*)d_in[3];
    const float* Wk = (const float*)d_in[4];
    const float* bk = (const float*)d_in[5];
    const float* Wv = (const float*)d_in[6];
    const float* bv = (const float*)d_in[7];
    const float* Wo = (const float*)d_in[8];
    const float* bo = (const float*)d_in[9];
    const float* bias_table = (const float*)d_in[10];
    const int*   rel_idx    = (const int*)d_in[11];
    float* out = (float*)d_out;

    const size_t FEAT = (size_t)1024 * NTOK * DIM;
    const size_t FB   = FEAT * 2;
    const size_t WB   = (size_t)DIM * DIM * 2;
    char* ws = (char*)d_ws;
    unsigned short* Qb  = (unsigned short*)(ws + 0 * FB);
    unsigned short* Kb  = (unsigned short*)(ws + 1 * FB);
    unsigned short* Vb  = (unsigned short*)(ws + 2 * FB);
    unsigned short* Lb  = (unsigned short*)(ws + 3 * FB);
    unsigned short* Ctx = (unsigned short*)(ws + 3 * FB); // aliases Lb (dead after Q GEMM)
    unsigned short* Ib  = (unsigned short*)(ws + 4 * FB);
    float* bias_dense   = (float*)(ws + 4 * FB);          // aliases Ib (dead after V GEMM)
    unsigned short* Wqb = (unsigned short*)(ws + 5 * FB + 0 * WB);
    unsigned short* Wkb = (unsigned short*)(ws + 5 * FB + 1 * WB);
    unsigned short* Wvb = (unsigned short*)(ws + 5 * FB + 2 * WB);
    unsigned short* Wob = (unsigned short*)(ws + 5 * FB + 3 * WB);

    cvt2_kernel<<<(int)(FEAT / 4 / 256), 256, 0, stream>>>(landmark, image, Lb, Ib, (int)FEAT);
    cvt2_kernel<<<(int)(DIM * DIM / 4 / 256), 256, 0, stream>>>(Wq, Wk, Wqb, Wkb, DIM * DIM);
    cvt2_kernel<<<(int)(DIM * DIM / 4 / 256), 256, 0, stream>>>(Wv, Wo, Wvb, Wob, DIM * DIM);

    dim3 ggrid(1024 / 128, 50176 / 128);
    gemm_bt_kernel<true><<<ggrid, 256, 0, stream>>>(Lb, Wqb, bq, Qb);
    gemm_bt_kernel<true><<<ggrid, 256, 0, stream>>>(Ib, Wkb, bk, Kb);
    gemm_bt_kernel<true><<<ggrid, 256, 0, stream>>>(Ib, Wvb, bv, Vb);

    bias_pre_kernel<<<HEADS, 256, 0, stream>>>(bias_table, rel_idx, bias_dense);

    attn_mfma_kernel<<<1024 * HEADS / 4, 256, 0, stream>>>(Qb, Kb, Vb, bias_dense, Ctx);

    gemm_bt_kernel<false><<<ggrid, 256, 0, stream>>>(Ctx, Wob, bo, out);
}